// Round 3
// baseline (3989.378 us; speedup 1.0000x reference)
//
#include <hip/hip_runtime.h>
#include <math.h>

#define GG 32
#define NN 1024
#define DD 4
#define HH 64
#define H2 128
#define KK 16
#define NEGF (-1e9f)

__device__ __forceinline__ float eluf(float x) {
    return x > 0.0f ? x : expm1f(x);
}

// ---------------- inputnet: f0 = elu((dn*x) @ Win + bin), valid = 1 ----------------
__global__ void k_input(const float* __restrict__ x, const float* __restrict__ dn,
                        const float* __restrict__ Win, const float* __restrict__ bin,
                        float* __restrict__ f0, int* __restrict__ valid) {
    int idx = blockIdx.x * blockDim.x + threadIdx.x;   // over G*N*H
    if (idx >= GG * NN * HH) return;
    int o = idx & (HH - 1);
    int node = idx >> 6;
    const float* xp = x + node * DD;
    float s = bin[o];
#pragma unroll
    for (int d = 0; d < DD; ++d)
        s = fmaf(dn[d] * xp[d], Win[d * HH + o], s);
    f0[idx] = eluf(s);
    if (o == 0) valid[node] = 1;
}

// ---------------- zero adjacency ----------------
__global__ void k_zero(unsigned int* __restrict__ p, int n) {
    int i = blockIdx.x * blockDim.x + threadIdx.x;
    if (i < n) p[i] = 0u;
}

// ---------------- kNN: per node, K smallest d2 (ties -> lowest index) ----------------
__global__ __launch_bounds__(256) void k_knn(const float* __restrict__ f, const int* __restrict__ valid,
                                             int* __restrict__ nbr) {
    int node = blockIdx.x;          // g*N + i
    if (!valid[node]) return;       // uniform per block
    int g = node >> 10;
    int i = node & (NN - 1);
    __shared__ float hi[HH];
    __shared__ float d2[NN];
    __shared__ float rv[256];
    __shared__ int   ri[256];
    int t = threadIdx.x;
    const float* fg = f + (size_t)g * NN * HH;
    if (t < HH) hi[t] = fg[i * HH + t];
    __syncthreads();
    for (int j = t; j < NN; j += 256) {
        float s;
        if (valid[(g << 10) + j]) {
            const float* fj = fg + j * HH;
            s = 0.0f;
#pragma unroll
            for (int d = 0; d < HH; ++d) {
                float df = fj[d] - hi[d];
                s = fmaf(df, df, s);
            }
        } else {
            s = __builtin_inff();
        }
        d2[j] = s;
    }
    __syncthreads();
    for (int k = 0; k < KK; ++k) {
        float lv = d2[t]; int li = t;
        for (int j = t + 256; j < NN; j += 256) {
            float v = d2[j];
            if (v < lv) { lv = v; li = j; }   // strict <: keeps lowest index on ties
        }
        rv[t] = lv; ri[t] = li;
        __syncthreads();
        for (int s2 = 128; s2 > 0; s2 >>= 1) {
            if (t < s2) {
                float v2 = rv[t + s2]; int i2 = ri[t + s2];
                if (v2 < rv[t] || (v2 == rv[t] && i2 < ri[t])) { rv[t] = v2; ri[t] = i2; }
            }
            __syncthreads();
        }
        if (t == 0) { nbr[node * KK + k] = ri[0]; d2[ri[0]] = __builtin_inff(); }
        __syncthreads();
    }
}

// ---------------- mark symmetric adjacency bits ----------------
__global__ void k_mark(const int* __restrict__ nbr, const int* __restrict__ valid,
                       unsigned int* __restrict__ adj) {
    int node = blockIdx.x * blockDim.x + threadIdx.x;
    if (node >= GG * NN) return;
    if (!valid[node]) return;
    int g = node >> 10, i = node & (NN - 1);
    unsigned int* arow = adj + (size_t)g * NN * 32;
    for (int k = 0; k < KK; ++k) {
        int j = nbr[node * KK + k];
        if (j < 0 || j >= NN) continue;
        if (!valid[(g << 10) + j]) continue;
        atomicOr(&arow[i * 32 + (j >> 5)], 1u << (j & 31));
        atomicOr(&arow[j * 32 + (i >> 5)], 1u << (i & 31));
    }
}

// ---------------- A = h@(W1top - W1bot) + b1 ; B = h@W1bot ----------------
__global__ __launch_bounds__(128) void k_ab(const float* __restrict__ f, const float* __restrict__ W1,
                                            const float* __restrict__ b1,
                                            float* __restrict__ A, float* __restrict__ Bv) {
    int node = blockIdx.x;
    int o = threadIdx.x;   // 0..127
    __shared__ float hs[HH];
    const float* fp = f + (size_t)node * HH;
    if (o < HH) hs[o] = fp[o];
    __syncthreads();
    float a = b1[o], b = 0.0f;
#pragma unroll 8
    for (int d = 0; d < HH; ++d) {
        float top = W1[d * H2 + o];
        float bot = W1[(HH + d) * H2 + o];
        a = fmaf(hs[d], top - bot, a);
        b = fmaf(hs[d], bot, b);
    }
    A[(size_t)node * H2 + o] = a;
    Bv[(size_t)node * H2 + o] = b;
}

// ---------------- EdgeConv: xn[c] = sum_r elu( elu(A[c]+B[r]) @ W2 + b2 ) ----------------
__global__ __launch_bounds__(128) void k_edgeconv(const float* __restrict__ A, const float* __restrict__ Bv,
                                                  const float* __restrict__ W2, const float* __restrict__ b2,
                                                  const unsigned int* __restrict__ adj,
                                                  const int* __restrict__ valid,
                                                  float* __restrict__ f1) {
    int node = blockIdx.x;    // g*N + c
    int t = threadIdx.x;      // 0..127
    if (!valid[node]) {
        if (t < HH) f1[(size_t)node * HH + t] = 0.0f;
        return;
    }
    int g = node >> 10;
    __shared__ float W2s[H2 * HH];      // 32 KB
    __shared__ unsigned short nl[NN];
    __shared__ float hid[H2];
    __shared__ float phid[HH];
    __shared__ unsigned int words[32];
    __shared__ int ofs[32];
    __shared__ int ne_s;
    for (int idx = t; idx < H2 * HH; idx += 128) W2s[idx] = W2[idx];
    const unsigned int* arow = adj + (size_t)node * 32;
    if (t < 32) words[t] = arow[t];
    __syncthreads();
    if (t == 0) {
        int s = 0;
        for (int w = 0; w < 32; ++w) { ofs[w] = s; s += __popc(words[w]); }
        ne_s = s;
    }
    __syncthreads();
    if (t < 32) {
        unsigned int w = words[t]; int p = ofs[t];
        while (w) { int b = __ffs(w) - 1; w &= w - 1; nl[p++] = (unsigned short)(t * 32 + b); }
    }
    __syncthreads();
    int ne = ne_s;
    float ac = A[(size_t)node * H2 + t];
    float b2r = (t < HH) ? b2[t] : 0.0f;
    float acc = 0.0f;
    const float* Bg = Bv + (size_t)g * NN * H2;
    int o = t & (HH - 1);
    int half = t >> 6;   // wave 0 / wave 1
    for (int e = 0; e < ne; ++e) {
        int r = nl[e];
        float h = eluf(ac + Bg[(size_t)r * H2 + t]);
        hid[t] = h;
        __syncthreads();
        float p = 0.0f;
#pragma unroll 8
        for (int hh = 0; hh < HH; ++hh)
            p = fmaf(hid[half * HH + hh], W2s[(half * HH + hh) * HH + o], p);
        if (half) phid[o] = p;
        __syncthreads();
        if (!half) acc += eluf(p + phid[o] + b2r);
        __syncthreads();
    }
    if (t < HH) f1[(size_t)node * HH + t] = acc;
}

// ---------------- deg -> inv ----------------
__global__ void k_deginv(const unsigned int* __restrict__ adj, const int* __restrict__ valid,
                         float* __restrict__ inv) {
    int node = blockIdx.x * blockDim.x + threadIdx.x;
    if (node >= GG * NN) return;
    if (!valid[node]) { inv[node] = 0.0f; return; }
    const unsigned int* arow = adj + (size_t)node * 32;
    int deg = 0;
#pragma unroll
    for (int w = 0; w < 32; ++w) deg += __popc(arow[w]);
    float d = (float)deg;
    inv[node] = d > 0.0f ? 1.0f / fmaxf(d, 1.0f) : 0.0f;
}

// ---------------- graclus best-match per node ----------------
__global__ __launch_bounds__(64) void k_graclus(const float* __restrict__ f1,
                                                const unsigned int* __restrict__ adj,
                                                const float* __restrict__ inv,
                                                const int* __restrict__ valid,
                                                int* __restrict__ bcol) {
    int node = blockIdx.x;
    int t = threadIdx.x;   // 0..63
    if (!valid[node]) { if (t == 0) bcol[node] = -1; return; }
    int g = node >> 10, r = node & (NN - 1);
    __shared__ unsigned short nl[NN];
    __shared__ unsigned int words[32];
    __shared__ int ofs[32];
    __shared__ int ne_s;
    const unsigned int* arow = adj + (size_t)node * 32;
    if (t < 32) words[t] = arow[t];
    __syncthreads();
    if (t == 0) {
        int s = 0;
        for (int w = 0; w < 32; ++w) { ofs[w] = s; s += __popc(words[w]); }
        ne_s = s;
    }
    __syncthreads();
    if (t < 32) {
        unsigned int w = words[t]; int p = ofs[t];
        while (w) { int b = __ffs(w) - 1; w &= w - 1; nl[p++] = (unsigned short)(t * 32 + b); }
    }
    __syncthreads();
    int ne = ne_s;
    const float* fg = f1 + (size_t)g * NN * HH;
    float xr = fg[r * HH + t];
    float invr = inv[node];
    int gbase = node & ~(NN - 1);
    float bw = NEGF; int bc = -1;
    for (int e = 0; e < ne; ++e) {
        int c = nl[e];
        if (c == r) continue;
        float df = xr - fg[c * HH + t];
        float s = df * df;
#pragma unroll
        for (int m = 32; m > 0; m >>= 1) s += __shfl_xor(s, m);
        float w = sqrtf(s + 1e-12f) * (invr + inv[gbase + c]);
        if (w > bw) { bw = w; bc = c; }
        else if (w == bw && c > bc) { bc = c; }
    }
    if (t == 0) bcol[node] = bc;
}

// ---------------- mutual match + pair max-pool (f1 -> f0, update valid) ----------------
__global__ __launch_bounds__(256) void k_pool(const float* __restrict__ f1, const int* __restrict__ bcol,
                                              int* __restrict__ valid, float* __restrict__ f0) {
    int t = threadIdx.x;
    int node = blockIdx.x * 4 + (t >> 6);
    int d = t & 63;
    int vs = valid[node];
    int j = bcol[node];
    int gbase = node & ~(NN - 1);
    int r = node & (NN - 1);
    bool mutual = vs && (j >= 0) && (bcol[gbase + j] == r);
    float out; int nv;
    if (mutual) {
        if (r < j) {
            out = fmaxf(f1[(size_t)node * HH + d], f1[(size_t)(gbase + j) * HH + d]);
            nv = 1;
        } else { out = 0.0f; nv = 0; }
    } else if (vs) {
        out = f1[(size_t)node * HH + d];
        nv = 1;
    } else { out = 0.0f; nv = 0; }
    f0[(size_t)node * HH + d] = out;
    if (d == 0) valid[node] = nv;
}

// ---------------- global max-pool + head MLP ----------------
__global__ __launch_bounds__(64) void k_head(const float* __restrict__ f0, const int* __restrict__ valid,
                                             const float* __restrict__ Wo1, const float* __restrict__ bo1,
                                             const float* __restrict__ Wo2, const float* __restrict__ bo2,
                                             const float* __restrict__ Wo3, const float* __restrict__ bo3,
                                             float* __restrict__ out) {
    int gidx = blockIdx.x;
    int t = threadIdx.x;   // 0..63
    const float* fg = f0 + (size_t)gidx * NN * HH;
    const int* vg = valid + gidx * NN;
    float m = NEGF;
    for (int s = 0; s < NN; ++s)
        if (vg[s]) m = fmaxf(m, fg[s * HH + t]);
    __shared__ float ga[HH], hb[HH], hc[HH];
    ga[t] = m;
    __syncthreads();
    float s1 = bo1[t];
    for (int d = 0; d < HH; ++d) s1 = fmaf(ga[d], Wo1[d * HH + t], s1);
    hb[t] = eluf(s1);
    __syncthreads();
    float s2 = bo2[t];
    for (int d = 0; d < HH; ++d) s2 = fmaf(hb[d], Wo2[d * HH + t], s2);
    hc[t] = eluf(s2);
    __syncthreads();
    float p = hc[t] * Wo3[t];
#pragma unroll
    for (int m2 = 32; m2 > 0; m2 >>= 1) p += __shfl_xor(p, m2);
    if (t == 0) out[gidx] = p + bo3[0];
}

extern "C" void kernel_launch(void* const* d_in, const int* in_sizes, int n_in,
                              void* d_out, int out_size, void* d_ws, size_t ws_size,
                              hipStream_t stream) {
    const float* x   = (const float*)d_in[0];
    const float* dn  = (const float*)d_in[1];
    const float* Win = (const float*)d_in[2];
    const float* bin = (const float*)d_in[3];
    const float* W1[2] = {(const float*)d_in[4], (const float*)d_in[8]};
    const float* b1[2] = {(const float*)d_in[5], (const float*)d_in[9]};
    const float* W2[2] = {(const float*)d_in[6], (const float*)d_in[10]};
    const float* b2[2] = {(const float*)d_in[7], (const float*)d_in[11]};
    const float* Wo1 = (const float*)d_in[12];
    const float* bo1 = (const float*)d_in[13];
    const float* Wo2 = (const float*)d_in[14];
    const float* bo2 = (const float*)d_in[15];
    const float* Wo3 = (const float*)d_in[16];
    const float* bo3 = (const float*)d_in[17];
    float* out = (float*)d_out;

    // Workspace layout (bytes):
    size_t need = 0;
    size_t off_f0 = need;  need += (size_t)GG * NN * HH * 4;   // 8 MB
    size_t off_f1 = need;  need += (size_t)GG * NN * HH * 4;   // 8 MB
    size_t off_A  = need;  need += (size_t)GG * NN * H2 * 4;   // 16 MB
    size_t off_B  = need;  need += (size_t)GG * NN * H2 * 4;   // 16 MB
    size_t off_adj= need;  need += (size_t)GG * NN * 32 * 4;   // 4 MB
    size_t off_nbr= need;  need += (size_t)GG * NN * KK * 4;   // 2 MB
    size_t off_v  = need;  need += (size_t)GG * NN * 4;
    size_t off_inv= need;  need += (size_t)GG * NN * 4;
    size_t off_bc = need;  need += (size_t)GG * NN * 4;
    if (ws_size < need) return;   // fail clean (absmax) instead of faulting the GPU

    char* ws = (char*)d_ws;
    float* f0 = (float*)(ws + off_f0);
    float* f1 = (float*)(ws + off_f1);
    float* Aa = (float*)(ws + off_A);
    float* Bv = (float*)(ws + off_B);
    unsigned int* adj = (unsigned int*)(ws + off_adj);
    int* nbr = (int*)(ws + off_nbr);
    int* valid = (int*)(ws + off_v);
    float* inv = (float*)(ws + off_inv);
    int* bcol = (int*)(ws + off_bc);

    k_input<<<(GG * NN * HH) / 256, 256, 0, stream>>>(x, dn, Win, bin, f0, valid);
    for (int L = 0; L < 2; ++L) {
        k_zero<<<(GG * NN * 32 + 255) / 256, 256, 0, stream>>>(adj, GG * NN * 32);
        k_knn<<<GG * NN, 256, 0, stream>>>(f0, valid, nbr);
        k_mark<<<(GG * NN) / 256, 256, 0, stream>>>(nbr, valid, adj);
        k_ab<<<GG * NN, 128, 0, stream>>>(f0, W1[L], b1[L], Aa, Bv);
        k_edgeconv<<<GG * NN, 128, 0, stream>>>(Aa, Bv, W2[L], b2[L], adj, valid, f1);
        k_deginv<<<(GG * NN) / 256, 256, 0, stream>>>(adj, valid, inv);
        k_graclus<<<GG * NN, 64, 0, stream>>>(f1, adj, inv, valid, bcol);
        k_pool<<<(GG * NN) / 4, 256, 0, stream>>>(f1, bcol, valid, f0);
    }
    k_head<<<GG, 64, 0, stream>>>(f0, valid, Wo1, bo1, Wo2, bo2, Wo3, bo3, out);
}

// Round 6
// 2798.970 us; speedup vs baseline: 1.4253x; 1.4253x over previous
//
#include <hip/hip_runtime.h>
#include <math.h>

#define GG 32
#define NN 1024
#define DD 4
#define HH 64
#define H2 128
#define KK 16
#define NEGF (-1e9f)

__device__ __forceinline__ float eluf(float x) {
    return x > 0.0f ? x : expm1f(x);
}

// ---------------- inputnet: f0 = elu((dn*x) @ Win + bin), valid = 1 ----------------
__global__ void k_input(const float* __restrict__ x, const float* __restrict__ dn,
                        const float* __restrict__ Win, const float* __restrict__ bin,
                        float* __restrict__ f0, int* __restrict__ valid) {
    int idx = blockIdx.x * blockDim.x + threadIdx.x;   // over G*N*H
    if (idx >= GG * NN * HH) return;
    int o = idx & (HH - 1);
    int node = idx >> 6;
    const float* xp = x + node * DD;
    float s = bin[o];
#pragma unroll
    for (int d = 0; d < DD; ++d)
        s = fmaf(dn[d] * xp[d], Win[d * HH + o], s);
    f0[idx] = eluf(s);
    if (o == 0) valid[node] = 1;
}

// ---------------- zero adjacency ----------------
__global__ void k_zero(unsigned int* __restrict__ p, int n) {
    int i = blockIdx.x * blockDim.x + threadIdx.x;
    if (i < n) p[i] = 0u;
}

// ---------------- kNN: 1 wave per query node, 8 waves/block share LDS candidate tiles.
// Distances bit-exact vs reference order (d ascending, fmaf). Selection = wave-local
// shfl argmin with lowest-index tie-break (matches stable top_k). No barriers in selection.
__global__ __launch_bounds__(512) void k_knn(const float* __restrict__ f, const int* __restrict__ valid,
                                             int* __restrict__ nbr) {
    const float INF = __builtin_inff();
    int t = threadIdx.x;
    int lane = t & 63;
    int wave = t >> 6;                       // 0..7
    int node = blockIdx.x * 8 + wave;        // block never straddles graphs (8 | 1024)
    int g = node >> 10;
    int row = node & (NN - 1);
    int gbase = g << 10;
    const float* fg = f + (size_t)g * NN * HH;

    __shared__ float4 ct4[64 * 16];          // 64 candidates x 64 dims, XOR-swizzled 16B slots
    __shared__ float pen[NN];                // 0 if valid candidate else +inf

    // stage validity penalties once (visible after first tile barrier)
    for (int j = t; j < NN; j += 512) pen[j] = valid[gbase + j] ? 0.0f : INF;

    // query features in registers (static-indexed)
    float q[HH];
    const float4* qsrc = (const float4*)(fg + (size_t)row * HH);
#pragma unroll
    for (int i = 0; i < 16; ++i) {
        float4 v = qsrc[i];
        q[4 * i + 0] = v.x; q[4 * i + 1] = v.y; q[4 * i + 2] = v.z; q[4 * i + 3] = v.w;
    }

    float dl[16];                            // per-lane distances: candidate j = m*64 + lane

    int c = t >> 3;                          // staging: candidate within tile (0..63)
    int part = t & 7;                        // 8 threads per candidate, 2 float4 each
#pragma unroll
    for (int tt = 0; tt < 16; ++tt) {
        // --- stage tile tt: 64 candidates x 64 dims, swizzled ---
        const float4* src = (const float4*)(fg + (size_t)(tt * 64 + c) * HH) + part * 2;
        float4 a0 = src[0];
        float4 a1 = src[1];
        int q40 = part * 2, q41 = part * 2 + 1;
        ct4[c * 16 + (q40 ^ (c & 7))] = a0;
        ct4[c * 16 + (q41 ^ (c & 7))] = a1;
        __syncthreads();
        // --- compute: this wave's query vs candidate (tt*64 + lane) ---
        float s = 0.0f;
#pragma unroll
        for (int i = 0; i < 16; ++i) {
            float4 cv = ct4[lane * 16 + (i ^ (lane & 7))];
            float d0 = cv.x - q[4 * i + 0]; s = fmaf(d0, d0, s);
            float d1 = cv.y - q[4 * i + 1]; s = fmaf(d1, d1, s);
            float d2 = cv.z - q[4 * i + 2]; s = fmaf(d2, d2, s);
            float d3 = cv.w - q[4 * i + 3]; s = fmaf(d3, d3, s);
        }
        dl[tt] = s + pen[tt * 64 + lane];
        __syncthreads();
    }

    // --- selection: K serial wave-argmin extractions, lowest-index tie-break ---
    float lv = dl[0]; int li = lane;
#pragma unroll
    for (int m = 1; m < 16; ++m) {
        if (dl[m] < lv) { lv = dl[m]; li = m * 64 + lane; }
    }
    for (int k = 0; k < KK; ++k) {
        float gv = lv; int gi = li;
#pragma unroll
        for (int off = 32; off > 0; off >>= 1) {
            float ov = __shfl_xor(gv, off);
            int oi = __shfl_xor(gi, off);
            if (ov < gv || (ov == gv && oi < gi)) { gv = ov; gi = oi; }
        }
        if (lane == 0) nbr[node * KK + k] = gi;
        if ((gi & 63) == lane) {
            int mrem = gi >> 6;
#pragma unroll
            for (int m = 0; m < 16; ++m)
                if (m == mrem) dl[m] = INF;
            lv = dl[0]; li = lane;
#pragma unroll
            for (int m = 1; m < 16; ++m)
                if (dl[m] < lv) { lv = dl[m]; li = m * 64 + lane; }
        }
    }
}

// ---------------- mark symmetric adjacency bits ----------------
__global__ void k_mark(const int* __restrict__ nbr, const int* __restrict__ valid,
                       unsigned int* __restrict__ adj) {
    int node = blockIdx.x * blockDim.x + threadIdx.x;
    if (node >= GG * NN) return;
    if (!valid[node]) return;
    int g = node >> 10, i = node & (NN - 1);
    unsigned int* arow = adj + (size_t)g * NN * 32;
    for (int k = 0; k < KK; ++k) {
        int j = nbr[node * KK + k];
        if (j < 0 || j >= NN) continue;
        if (!valid[(g << 10) + j]) continue;
        atomicOr(&arow[i * 32 + (j >> 5)], 1u << (j & 31));
        atomicOr(&arow[j * 32 + (i >> 5)], 1u << (i & 31));
    }
}

// ---------------- A = h@(W1top - W1bot) + b1 ; B = h@W1bot ----------------
__global__ __launch_bounds__(128) void k_ab(const float* __restrict__ f, const float* __restrict__ W1,
                                            const float* __restrict__ b1,
                                            float* __restrict__ A, float* __restrict__ Bv) {
    int node = blockIdx.x;
    int o = threadIdx.x;   // 0..127
    __shared__ float hs[HH];
    const float* fp = f + (size_t)node * HH;
    if (o < HH) hs[o] = fp[o];
    __syncthreads();
    float a = b1[o], b = 0.0f;
#pragma unroll 8
    for (int d = 0; d < HH; ++d) {
        float top = W1[d * H2 + o];
        float bot = W1[(HH + d) * H2 + o];
        a = fmaf(hs[d], top - bot, a);
        b = fmaf(hs[d], bot, b);
    }
    A[(size_t)node * H2 + o] = a;
    Bv[(size_t)node * H2 + o] = b;
}

// ---------------- bit-scan edge iterator (ascending r) ----------------
__device__ __forceinline__ int next_edge(const unsigned int* __restrict__ arow,
                                         int& w, unsigned int& bits) {
    while (bits == 0u) {
        if (++w >= 32) return -1;
        bits = arow[w];
    }
    int b = __ffs(bits) - 1;
    bits &= bits - 1;
    return (w << 5) + b;
}

// ---------------- EdgeConv: one wave per node, zero barriers.
// lane = output o; W2[:,o] in 128 VGPRs; hid broadcast via wave-private LDS row.
// acc order: ascending r (matches sorted-code segment_sum); dot = 4 partial chains.
__global__ __launch_bounds__(256, 2) void k_edgeconv(const float* __restrict__ A,
                                                     const float* __restrict__ Bv,
                                                     const float* __restrict__ W2,
                                                     const float* __restrict__ b2,
                                                     const unsigned int* __restrict__ adj,
                                                     const int* __restrict__ valid,
                                                     float* __restrict__ f1) {
    __shared__ float hid[4][H2];             // one 512B row per wave
    int t = threadIdx.x;
    int lane = t & 63;
    int wave = t >> 6;                       // 0..3
    int node = blockIdx.x * 4 + wave;
    int g = node >> 10;

    if (!valid[node]) {
        f1[(size_t)node * HH + lane] = 0.0f;
        return;                               // wave-uniform; no barriers in this kernel
    }

    // W2 column for this lane's output: 128 VGPRs, coalesced loads (L1-resident)
    float w2[H2];
#pragma unroll
    for (int h = 0; h < H2; ++h) w2[h] = W2[h * HH + lane];

    float ac_lo = A[(size_t)node * H2 + lane];
    float ac_hi = A[(size_t)node * H2 + 64 + lane];
    float b2r = b2[lane];
    const float* Bg = Bv + (size_t)g * NN * H2;
    const unsigned int* arow = adj + (size_t)node * 32;
    float* hb = &hid[wave][0];

    float acc = 0.0f;
    int w = 0;
    unsigned int bits = arow[0];
    int r = next_edge(arow, w, bits);
    float blo = 0.0f, bhi = 0.0f;
    if (r >= 0) {
        blo = Bg[(size_t)r * H2 + lane];
        bhi = Bg[(size_t)r * H2 + 64 + lane];
    }
    while (r >= 0) {
        // prefetch next edge's B row over the current dot
        int rn = next_edge(arow, w, bits);
        float nlo = 0.0f, nhi = 0.0f;
        if (rn >= 0) {
            nlo = Bg[(size_t)rn * H2 + lane];
            nhi = Bg[(size_t)rn * H2 + 64 + lane];
        }
        float hlo = eluf(ac_lo + blo);
        float hhi = eluf(ac_hi + bhi);
        hb[lane] = hlo;
        hb[64 + lane] = hhi;
        asm volatile("s_waitcnt lgkmcnt(0)" ::: "memory");   // cross-lane LDS visibility (same wave)
        __builtin_amdgcn_sched_barrier(0);
        float p0 = 0.0f, p1 = 0.0f, p2 = 0.0f, p3 = 0.0f;
#pragma unroll
        for (int j = 0; j < 32; ++j) {
            float4 h4 = *(const float4*)(hb + 4 * j);        // uniform addr -> broadcast
            p0 = fmaf(h4.x, w2[4 * j + 0], p0);
            p1 = fmaf(h4.y, w2[4 * j + 1], p1);
            p2 = fmaf(h4.z, w2[4 * j + 2], p2);
            p3 = fmaf(h4.w, w2[4 * j + 3], p3);
        }
        acc += eluf(((p0 + p1) + (p2 + p3)) + b2r);
        r = rn; blo = nlo; bhi = nhi;
    }
    f1[(size_t)node * HH + lane] = acc;
}

// ---------------- deg -> inv ----------------
__global__ void k_deginv(const unsigned int* __restrict__ adj, const int* __restrict__ valid,
                         float* __restrict__ inv) {
    int node = blockIdx.x * blockDim.x + threadIdx.x;
    if (node >= GG * NN) return;
    if (!valid[node]) { inv[node] = 0.0f; return; }
    const unsigned int* arow = adj + (size_t)node * 32;
    int deg = 0;
#pragma unroll
    for (int w = 0; w < 32; ++w) deg += __popc(arow[w]);
    float d = (float)deg;
    inv[node] = d > 0.0f ? 1.0f / fmaxf(d, 1.0f) : 0.0f;
}

// ---------------- graclus best-match per node ----------------
__global__ __launch_bounds__(64) void k_graclus(const float* __restrict__ f1,
                                                const unsigned int* __restrict__ adj,
                                                const float* __restrict__ inv,
                                                const int* __restrict__ valid,
                                                int* __restrict__ bcol) {
    int node = blockIdx.x;
    int t = threadIdx.x;   // 0..63
    if (!valid[node]) { if (t == 0) bcol[node] = -1; return; }
    int g = node >> 10, r = node & (NN - 1);
    __shared__ unsigned short nl[NN];
    __shared__ unsigned int words[32];
    __shared__ int ofs[32];
    __shared__ int ne_s;
    const unsigned int* arow = adj + (size_t)node * 32;
    if (t < 32) words[t] = arow[t];
    __syncthreads();
    if (t == 0) {
        int s = 0;
        for (int w = 0; w < 32; ++w) { ofs[w] = s; s += __popc(words[w]); }
        ne_s = s;
    }
    __syncthreads();
    if (t < 32) {
        unsigned int w = words[t]; int p = ofs[t];
        while (w) { int b = __ffs(w) - 1; w &= w - 1; nl[p++] = (unsigned short)(t * 32 + b); }
    }
    __syncthreads();
    int ne = ne_s;
    const float* fg = f1 + (size_t)g * NN * HH;
    float xr = fg[r * HH + t];
    float invr = inv[node];
    int gbase = node & ~(NN - 1);
    float bw = NEGF; int bc = -1;
    for (int e = 0; e < ne; ++e) {
        int c = nl[e];
        if (c == r) continue;
        float df = xr - fg[c * HH + t];
        float s = df * df;
#pragma unroll
        for (int m = 32; m > 0; m >>= 1) s += __shfl_xor(s, m);
        float w = sqrtf(s + 1e-12f) * (invr + inv[gbase + c]);
        if (w > bw) { bw = w; bc = c; }
        else if (w == bw && c > bc) { bc = c; }
    }
    if (t == 0) bcol[node] = bc;
}

// ---------------- mutual match + pair max-pool (f1 -> f0, update valid) ----------------
__global__ __launch_bounds__(256) void k_pool(const float* __restrict__ f1, const int* __restrict__ bcol,
                                              int* __restrict__ valid, float* __restrict__ f0) {
    int t = threadIdx.x;
    int node = blockIdx.x * 4 + (t >> 6);
    int d = t & 63;
    int vs = valid[node];
    int j = bcol[node];
    int gbase = node & ~(NN - 1);
    int r = node & (NN - 1);
    bool mutual = vs && (j >= 0) && (bcol[gbase + j] == r);
    float out; int nv;
    if (mutual) {
        if (r < j) {
            out = fmaxf(f1[(size_t)node * HH + d], f1[(size_t)(gbase + j) * HH + d]);
            nv = 1;
        } else { out = 0.0f; nv = 0; }
    } else if (vs) {
        out = f1[(size_t)node * HH + d];
        nv = 1;
    } else { out = 0.0f; nv = 0; }
    f0[(size_t)node * HH + d] = out;
    if (d == 0) valid[node] = nv;
}

// ---------------- global max-pool + head MLP ----------------
__global__ __launch_bounds__(64) void k_head(const float* __restrict__ f0, const int* __restrict__ valid,
                                             const float* __restrict__ Wo1, const float* __restrict__ bo1,
                                             const float* __restrict__ Wo2, const float* __restrict__ bo2,
                                             const float* __restrict__ Wo3, const float* __restrict__ bo3,
                                             float* __restrict__ out) {
    int gidx = blockIdx.x;
    int t = threadIdx.x;   // 0..63
    const float* fg = f0 + (size_t)gidx * NN * HH;
    const int* vg = valid + gidx * NN;
    float m = NEGF;
    for (int s = 0; s < NN; ++s)
        if (vg[s]) m = fmaxf(m, fg[s * HH + t]);
    __shared__ float ga[HH], hb[HH], hc[HH];
    ga[t] = m;
    __syncthreads();
    float s1 = bo1[t];
    for (int d = 0; d < HH; ++d) s1 = fmaf(ga[d], Wo1[d * HH + t], s1);
    hb[t] = eluf(s1);
    __syncthreads();
    float s2 = bo2[t];
    for (int d = 0; d < HH; ++d) s2 = fmaf(hb[d], Wo2[d * HH + t], s2);
    hc[t] = eluf(s2);
    __syncthreads();
    float p = hc[t] * Wo3[t];
#pragma unroll
    for (int m2 = 32; m2 > 0; m2 >>= 1) p += __shfl_xor(p, m2);
    if (t == 0) out[gidx] = p + bo3[0];
}

extern "C" void kernel_launch(void* const* d_in, const int* in_sizes, int n_in,
                              void* d_out, int out_size, void* d_ws, size_t ws_size,
                              hipStream_t stream) {
    const float* x   = (const float*)d_in[0];
    const float* dn  = (const float*)d_in[1];
    const float* Win = (const float*)d_in[2];
    const float* bin = (const float*)d_in[3];
    const float* W1[2] = {(const float*)d_in[4], (const float*)d_in[8]};
    const float* b1[2] = {(const float*)d_in[5], (const float*)d_in[9]};
    const float* W2[2] = {(const float*)d_in[6], (const float*)d_in[10]};
    const float* b2[2] = {(const float*)d_in[7], (const float*)d_in[11]};
    const float* Wo1 = (const float*)d_in[12];
    const float* bo1 = (const float*)d_in[13];
    const float* Wo2 = (const float*)d_in[14];
    const float* bo2 = (const float*)d_in[15];
    const float* Wo3 = (const float*)d_in[16];
    const float* bo3 = (const float*)d_in[17];
    float* out = (float*)d_out;

    // Workspace layout (bytes):
    size_t need = 0;
    size_t off_f0 = need;  need += (size_t)GG * NN * HH * 4;   // 8 MB
    size_t off_f1 = need;  need += (size_t)GG * NN * HH * 4;   // 8 MB
    size_t off_A  = need;  need += (size_t)GG * NN * H2 * 4;   // 16 MB
    size_t off_B  = need;  need += (size_t)GG * NN * H2 * 4;   // 16 MB
    size_t off_adj= need;  need += (size_t)GG * NN * 32 * 4;   // 4 MB
    size_t off_nbr= need;  need += (size_t)GG * NN * KK * 4;   // 2 MB
    size_t off_v  = need;  need += (size_t)GG * NN * 4;
    size_t off_inv= need;  need += (size_t)GG * NN * 4;
    size_t off_bc = need;  need += (size_t)GG * NN * 4;
    if (ws_size < need) return;   // fail clean (absmax) instead of faulting the GPU

    char* ws = (char*)d_ws;
    float* f0 = (float*)(ws + off_f0);
    float* f1 = (float*)(ws + off_f1);
    float* Aa = (float*)(ws + off_A);
    float* Bv = (float*)(ws + off_B);
    unsigned int* adj = (unsigned int*)(ws + off_adj);
    int* nbr = (int*)(ws + off_nbr);
    int* valid = (int*)(ws + off_v);
    float* inv = (float*)(ws + off_inv);
    int* bcol = (int*)(ws + off_bc);

    k_input<<<(GG * NN * HH) / 256, 256, 0, stream>>>(x, dn, Win, bin, f0, valid);
    for (int L = 0; L < 2; ++L) {
        k_zero<<<(GG * NN * 32 + 255) / 256, 256, 0, stream>>>(adj, GG * NN * 32);
        k_knn<<<GG * NN / 8, 512, 0, stream>>>(f0, valid, nbr);
        k_mark<<<(GG * NN) / 256, 256, 0, stream>>>(nbr, valid, adj);
        k_ab<<<GG * NN, 128, 0, stream>>>(f0, W1[L], b1[L], Aa, Bv);
        k_edgeconv<<<GG * NN / 4, 256, 0, stream>>>(Aa, Bv, W2[L], b2[L], adj, valid, f1);
        k_deginv<<<(GG * NN) / 256, 256, 0, stream>>>(adj, valid, inv);
        k_graclus<<<GG * NN, 64, 0, stream>>>(f1, adj, inv, valid, bcol);
        k_pool<<<(GG * NN) / 4, 256, 0, stream>>>(f1, bcol, valid, f0);
    }
    k_head<<<GG, 64, 0, stream>>>(f0, valid, Wo1, bo1, Wo2, bo2, Wo3, bo3, out);
}

// Round 7
// 2164.388 us; speedup vs baseline: 1.8432x; 1.2932x over previous
//
#include <hip/hip_runtime.h>
#include <math.h>

#define GG 32
#define NN 1024
#define DD 4
#define HH 64
#define H2 128
#define KK 16
#define NEGF (-1e9f)

__device__ __forceinline__ float eluf(float x) {
    return x > 0.0f ? x : expm1f(x);
}

__device__ __forceinline__ void gload_lds16(const float4* g, float4* l) {
    __builtin_amdgcn_global_load_lds((const __attribute__((address_space(1))) void*)g,
                                     (__attribute__((address_space(3))) void*)l, 16, 0, 0);
}

// ---------------- inputnet: f0 = elu((dn*x) @ Win + bin), valid = 1 ----------------
__global__ void k_input(const float* __restrict__ x, const float* __restrict__ dn,
                        const float* __restrict__ Win, const float* __restrict__ bin,
                        float* __restrict__ f0, int* __restrict__ valid) {
    int idx = blockIdx.x * blockDim.x + threadIdx.x;   // over G*N*H
    if (idx >= GG * NN * HH) return;
    int o = idx & (HH - 1);
    int node = idx >> 6;
    const float* xp = x + node * DD;
    float s = bin[o];
#pragma unroll
    for (int d = 0; d < DD; ++d)
        s = fmaf(dn[d] * xp[d], Win[d * HH + o], s);
    f0[idx] = eluf(s);
    if (o == 0) valid[node] = 1;
}

// ---------------- zero adjacency ----------------
__global__ void k_zero(unsigned int* __restrict__ p, int n) {
    int i = blockIdx.x * blockDim.x + threadIdx.x;
    if (i < n) p[i] = 0u;
}

// ---------------- kNN: 1 wave per query, 8 waves/block, async double-buffered tiles.
// Staging: global_load_lds (linear LDS dest, inverse-swizzled global source).
// Read: slot i of row r at stored slot i^(r&7)  (same involution -> correct bytes).
// One barrier per tile; distances bit-exact (d ascending, fmaf); selection = shfl
// argmin with lowest-index tie-break. ----------------
__global__ __launch_bounds__(512) void k_knn(const float* __restrict__ f, const int* __restrict__ valid,
                                             int* __restrict__ nbr) {
    const float INF = __builtin_inff();
    int t = threadIdx.x;
    int lane = t & 63;
    int wave = t >> 6;                       // 0..7
    int node = blockIdx.x * 8 + wave;        // block never straddles graphs (8 | 1024)
    int g = node >> 10;
    int row = node & (NN - 1);
    int gbase = g << 10;
    const float* fg = f + (size_t)g * NN * HH;
    const float4* fg4 = (const float4*)fg;

    __shared__ float4 buf[2][1024];          // 2 x 16 KB candidate tiles (64 rows x 16 slots)
    __shared__ float pen[NN];                // 0 if valid candidate else +inf

    // issue async stage of tile 0 into buf[0] (2 calls/wave, wave-uniform LDS base)
#pragma unroll
    for (int c = 0; c < 2; ++c) {
        int o = wave * 128 + c * 64 + lane;          // float4 slot in tile
        int r = o >> 4;
        int sl = o & 15;
        gload_lds16(fg4 + (size_t)r * 16 + (sl ^ (r & 7)), &buf[0][wave * 128 + c * 64]);
    }

    // validity penalties (LDS stores; visible after first barrier)
    for (int j = t; j < NN; j += 512) pen[j] = valid[gbase + j] ? 0.0f : INF;

    // query features in registers (overlaps stage(0) flight)
    float q[HH];
    const float4* qsrc = fg4 + (size_t)row * 16;
#pragma unroll
    for (int i = 0; i < 16; ++i) {
        float4 v = qsrc[i];
        q[4 * i + 0] = v.x; q[4 * i + 1] = v.y; q[4 * i + 2] = v.z; q[4 * i + 3] = v.w;
    }

    float dl[16];                            // per-lane distances: candidate j = tt*64 + lane
    __syncthreads();                         // drains vmcnt -> buf[0] ready

    int cur = 0;
#pragma unroll 1
    for (int tt = 0; tt < 16; ++tt) {
        if (tt < 15) {
            // issue async stage of tile tt+1 into buf[cur^1]; lands during compute
#pragma unroll
            for (int c = 0; c < 2; ++c) {
                int o = wave * 128 + c * 64 + lane;
                int r = o >> 4;
                int sl = o & 15;
                gload_lds16(fg4 + (size_t)((tt + 1) * 64 + r) * 16 + (sl ^ (r & 7)),
                            &buf[cur ^ 1][wave * 128 + c * 64]);
            }
        }
        // compute: this wave's query vs candidate (tt*64 + lane)
        float s = 0.0f;
#pragma unroll
        for (int i = 0; i < 16; ++i) {
            float4 cv = buf[cur][lane * 16 + (i ^ (lane & 7))];
            float d0 = cv.x - q[4 * i + 0]; s = fmaf(d0, d0, s);
            float d1 = cv.y - q[4 * i + 1]; s = fmaf(d1, d1, s);
            float d2 = cv.z - q[4 * i + 2]; s = fmaf(d2, d2, s);
            float d3 = cv.w - q[4 * i + 3]; s = fmaf(d3, d3, s);
        }
        dl[tt] = s + pen[tt * 64 + lane];
        __syncthreads();                     // vmcnt(0)+lgkmcnt(0): next tile ready, buf[cur] reusable
        cur ^= 1;
    }

    // --- selection: K serial wave-argmin extractions, lowest-index tie-break ---
    float lv = dl[0]; int li = lane;
#pragma unroll
    for (int m = 1; m < 16; ++m) {
        if (dl[m] < lv) { lv = dl[m]; li = m * 64 + lane; }
    }
    for (int k = 0; k < KK; ++k) {
        float gv = lv; int gi = li;
#pragma unroll
        for (int off = 32; off > 0; off >>= 1) {
            float ov = __shfl_xor(gv, off);
            int oi = __shfl_xor(gi, off);
            if (ov < gv || (ov == gv && oi < gi)) { gv = ov; gi = oi; }
        }
        if (lane == 0) nbr[node * KK + k] = gi;
        if ((gi & 63) == lane) {
            int mrem = gi >> 6;
#pragma unroll
            for (int m = 0; m < 16; ++m)
                if (m == mrem) dl[m] = INF;
            lv = dl[0]; li = lane;
#pragma unroll
            for (int m = 1; m < 16; ++m)
                if (dl[m] < lv) { lv = dl[m]; li = m * 64 + lane; }
        }
    }
}

// ---------------- mark symmetric adjacency bits ----------------
__global__ void k_mark(const int* __restrict__ nbr, const int* __restrict__ valid,
                       unsigned int* __restrict__ adj) {
    int node = blockIdx.x * blockDim.x + threadIdx.x;
    if (node >= GG * NN) return;
    if (!valid[node]) return;
    int g = node >> 10, i = node & (NN - 1);
    unsigned int* arow = adj + (size_t)g * NN * 32;
    for (int k = 0; k < KK; ++k) {
        int j = nbr[node * KK + k];
        if (j < 0 || j >= NN) continue;
        if (!valid[(g << 10) + j]) continue;
        atomicOr(&arow[i * 32 + (j >> 5)], 1u << (j & 31));
        atomicOr(&arow[j * 32 + (i >> 5)], 1u << (i & 31));
    }
}

// ---------------- A = h@(W1top - W1bot) + b1 ; B = h@W1bot ----------------
__global__ __launch_bounds__(128) void k_ab(const float* __restrict__ f, const float* __restrict__ W1,
                                            const float* __restrict__ b1,
                                            float* __restrict__ A, float* __restrict__ Bv) {
    int node = blockIdx.x;
    int o = threadIdx.x;   // 0..127
    __shared__ float hs[HH];
    const float* fp = f + (size_t)node * HH;
    if (o < HH) hs[o] = fp[o];
    __syncthreads();
    float a = b1[o], b = 0.0f;
#pragma unroll 8
    for (int d = 0; d < HH; ++d) {
        float top = W1[d * H2 + o];
        float bot = W1[(HH + d) * H2 + o];
        a = fmaf(hs[d], top - bot, a);
        b = fmaf(hs[d], bot, b);
    }
    A[(size_t)node * H2 + o] = a;
    Bv[(size_t)node * H2 + o] = b;
}

// ---------------- bit-scan edge iterator (ascending r) ----------------
__device__ __forceinline__ int next_edge(const unsigned int* __restrict__ arow,
                                         int& w, unsigned int& bits) {
    while (bits == 0u) {
        if (++w >= 32) return -1;
        bits = arow[w];
    }
    int b = __ffs(bits) - 1;
    bits &= bits - 1;
    return (w << 5) + b;
}

// ---------------- EdgeConv: one wave per node, zero barriers.
// lane = output o; W2[:,o] in 128 VGPRs; hid broadcast via wave-private LDS row.
// acc order: ascending r (matches sorted-code segment_sum); dot = 4 partial chains.
__global__ __launch_bounds__(256, 2) void k_edgeconv(const float* __restrict__ A,
                                                     const float* __restrict__ Bv,
                                                     const float* __restrict__ W2,
                                                     const float* __restrict__ b2,
                                                     const unsigned int* __restrict__ adj,
                                                     const int* __restrict__ valid,
                                                     float* __restrict__ f1) {
    __shared__ float hid[4][H2];             // one 512B row per wave
    int t = threadIdx.x;
    int lane = t & 63;
    int wave = t >> 6;                       // 0..3
    int node = blockIdx.x * 4 + wave;
    int g = node >> 10;

    if (!valid[node]) {
        f1[(size_t)node * HH + lane] = 0.0f;
        return;                               // wave-uniform; no barriers in this kernel
    }

    // W2 column for this lane's output: 128 VGPRs, coalesced loads (L1-resident)
    float w2[H2];
#pragma unroll
    for (int h = 0; h < H2; ++h) w2[h] = W2[h * HH + lane];

    float ac_lo = A[(size_t)node * H2 + lane];
    float ac_hi = A[(size_t)node * H2 + 64 + lane];
    float b2r = b2[lane];
    const float* Bg = Bv + (size_t)g * NN * H2;
    const unsigned int* arow = adj + (size_t)node * 32;
    float* hb = &hid[wave][0];

    float acc = 0.0f;
    int w = 0;
    unsigned int bits = arow[0];
    int r = next_edge(arow, w, bits);
    float blo = 0.0f, bhi = 0.0f;
    if (r >= 0) {
        blo = Bg[(size_t)r * H2 + lane];
        bhi = Bg[(size_t)r * H2 + 64 + lane];
    }
    while (r >= 0) {
        // prefetch next edge's B row over the current dot
        int rn = next_edge(arow, w, bits);
        float nlo = 0.0f, nhi = 0.0f;
        if (rn >= 0) {
            nlo = Bg[(size_t)rn * H2 + lane];
            nhi = Bg[(size_t)rn * H2 + 64 + lane];
        }
        float hlo = eluf(ac_lo + blo);
        float hhi = eluf(ac_hi + bhi);
        hb[lane] = hlo;
        hb[64 + lane] = hhi;
        asm volatile("s_waitcnt lgkmcnt(0)" ::: "memory");   // cross-lane LDS visibility (same wave)
        __builtin_amdgcn_sched_barrier(0);
        float p0 = 0.0f, p1 = 0.0f, p2 = 0.0f, p3 = 0.0f;
#pragma unroll
        for (int j = 0; j < 32; ++j) {
            float4 h4 = *(const float4*)(hb + 4 * j);        // uniform addr -> broadcast
            p0 = fmaf(h4.x, w2[4 * j + 0], p0);
            p1 = fmaf(h4.y, w2[4 * j + 1], p1);
            p2 = fmaf(h4.z, w2[4 * j + 2], p2);
            p3 = fmaf(h4.w, w2[4 * j + 3], p3);
        }
        acc += eluf(((p0 + p1) + (p2 + p3)) + b2r);
        r = rn; blo = nlo; bhi = nhi;
    }
    f1[(size_t)node * HH + lane] = acc;
}

// ---------------- deg -> inv ----------------
__global__ void k_deginv(const unsigned int* __restrict__ adj, const int* __restrict__ valid,
                         float* __restrict__ inv) {
    int node = blockIdx.x * blockDim.x + threadIdx.x;
    if (node >= GG * NN) return;
    if (!valid[node]) { inv[node] = 0.0f; return; }
    const unsigned int* arow = adj + (size_t)node * 32;
    int deg = 0;
#pragma unroll
    for (int w = 0; w < 32; ++w) deg += __popc(arow[w]);
    float d = (float)deg;
    inv[node] = d > 0.0f ? 1.0f / fmaxf(d, 1.0f) : 0.0f;
}

// ---------------- graclus best-match per node ----------------
__global__ __launch_bounds__(64) void k_graclus(const float* __restrict__ f1,
                                                const unsigned int* __restrict__ adj,
                                                const float* __restrict__ inv,
                                                const int* __restrict__ valid,
                                                int* __restrict__ bcol) {
    int node = blockIdx.x;
    int t = threadIdx.x;   // 0..63
    if (!valid[node]) { if (t == 0) bcol[node] = -1; return; }
    int g = node >> 10, r = node & (NN - 1);
    __shared__ unsigned short nl[NN];
    __shared__ unsigned int words[32];
    __shared__ int ofs[32];
    __shared__ int ne_s;
    const unsigned int* arow = adj + (size_t)node * 32;
    if (t < 32) words[t] = arow[t];
    __syncthreads();
    if (t == 0) {
        int s = 0;
        for (int w = 0; w < 32; ++w) { ofs[w] = s; s += __popc(words[w]); }
        ne_s = s;
    }
    __syncthreads();
    if (t < 32) {
        unsigned int w = words[t]; int p = ofs[t];
        while (w) { int b = __ffs(w) - 1; w &= w - 1; nl[p++] = (unsigned short)(t * 32 + b); }
    }
    __syncthreads();
    int ne = ne_s;
    const float* fg = f1 + (size_t)g * NN * HH;
    float xr = fg[r * HH + t];
    float invr = inv[node];
    int gbase = node & ~(NN - 1);
    float bw = NEGF; int bc = -1;
    for (int e = 0; e < ne; ++e) {
        int c = nl[e];
        if (c == r) continue;
        float df = xr - fg[c * HH + t];
        float s = df * df;
#pragma unroll
        for (int m = 32; m > 0; m >>= 1) s += __shfl_xor(s, m);
        float w = sqrtf(s + 1e-12f) * (invr + inv[gbase + c]);
        if (w > bw) { bw = w; bc = c; }
        else if (w == bw && c > bc) { bc = c; }
    }
    if (t == 0) bcol[node] = bc;
}

// ---------------- mutual match + pair max-pool (f1 -> f0, update valid) ----------------
__global__ __launch_bounds__(256) void k_pool(const float* __restrict__ f1, const int* __restrict__ bcol,
                                              int* __restrict__ valid, float* __restrict__ f0) {
    int t = threadIdx.x;
    int node = blockIdx.x * 4 + (t >> 6);
    int d = t & 63;
    int vs = valid[node];
    int j = bcol[node];
    int gbase = node & ~(NN - 1);
    int r = node & (NN - 1);
    bool mutual = vs && (j >= 0) && (bcol[gbase + j] == r);
    float out; int nv;
    if (mutual) {
        if (r < j) {
            out = fmaxf(f1[(size_t)node * HH + d], f1[(size_t)(gbase + j) * HH + d]);
            nv = 1;
        } else { out = 0.0f; nv = 0; }
    } else if (vs) {
        out = f1[(size_t)node * HH + d];
        nv = 1;
    } else { out = 0.0f; nv = 0; }
    f0[(size_t)node * HH + d] = out;
    if (d == 0) valid[node] = nv;
}

// ---------------- global max-pool + head MLP (4-wave sliced max) ----------------
__global__ __launch_bounds__(256) void k_head(const float* __restrict__ f0, const int* __restrict__ valid,
                                              const float* __restrict__ Wo1, const float* __restrict__ bo1,
                                              const float* __restrict__ Wo2, const float* __restrict__ bo2,
                                              const float* __restrict__ Wo3, const float* __restrict__ bo3,
                                              float* __restrict__ out) {
    int gidx = blockIdx.x;
    int t = threadIdx.x;   // 0..255
    int lane = t & 63;
    int w = t >> 6;        // 0..3
    const float* fg = f0 + (size_t)gidx * NN * HH;
    const int* vg = valid + gidx * NN;
    __shared__ float sm[4][HH];
    float m = NEGF;
    for (int s = w * 256; s < (w + 1) * 256; ++s)
        if (vg[s]) m = fmaxf(m, fg[s * HH + lane]);
    sm[w][lane] = m;
    __syncthreads();
    float mm = fmaxf(fmaxf(sm[0][lane], sm[1][lane]), fmaxf(sm[2][lane], sm[3][lane]));
    __shared__ float ga[HH], hb[HH], hc[HH];
    if (t < HH) ga[t] = mm;      // wave 0's lanes hold the same mm as others
    __syncthreads();
    float s1 = bo1[lane];
    for (int d = 0; d < HH; ++d) s1 = fmaf(ga[d], Wo1[d * HH + lane], s1);
    if (t < HH) hb[t] = eluf(s1);
    __syncthreads();
    float s2 = bo2[lane];
    for (int d = 0; d < HH; ++d) s2 = fmaf(hb[d], Wo2[d * HH + lane], s2);
    if (t < HH) hc[t] = eluf(s2);
    __syncthreads();
    if (w == 0) {
        float p = hc[lane] * Wo3[lane];
#pragma unroll
        for (int m2 = 32; m2 > 0; m2 >>= 1) p += __shfl_xor(p, m2);
        if (lane == 0) out[gidx] = p + bo3[0];
    }
}

extern "C" void kernel_launch(void* const* d_in, const int* in_sizes, int n_in,
                              void* d_out, int out_size, void* d_ws, size_t ws_size,
                              hipStream_t stream) {
    const float* x   = (const float*)d_in[0];
    const float* dn  = (const float*)d_in[1];
    const float* Win = (const float*)d_in[2];
    const float* bin = (const float*)d_in[3];
    const float* W1[2] = {(const float*)d_in[4], (const float*)d_in[8]};
    const float* b1[2] = {(const float*)d_in[5], (const float*)d_in[9]};
    const float* W2[2] = {(const float*)d_in[6], (const float*)d_in[10]};
    const float* b2[2] = {(const float*)d_in[7], (const float*)d_in[11]};
    const float* Wo1 = (const float*)d_in[12];
    const float* bo1 = (const float*)d_in[13];
    const float* Wo2 = (const float*)d_in[14];
    const float* bo2 = (const float*)d_in[15];
    const float* Wo3 = (const float*)d_in[16];
    const float* bo3 = (const float*)d_in[17];
    float* out = (float*)d_out;

    // Workspace layout (bytes):
    size_t need = 0;
    size_t off_f0 = need;  need += (size_t)GG * NN * HH * 4;   // 8 MB
    size_t off_f1 = need;  need += (size_t)GG * NN * HH * 4;   // 8 MB
    size_t off_A  = need;  need += (size_t)GG * NN * H2 * 4;   // 16 MB
    size_t off_B  = need;  need += (size_t)GG * NN * H2 * 4;   // 16 MB
    size_t off_adj= need;  need += (size_t)GG * NN * 32 * 4;   // 4 MB
    size_t off_nbr= need;  need += (size_t)GG * NN * KK * 4;   // 2 MB
    size_t off_v  = need;  need += (size_t)GG * NN * 4;
    size_t off_inv= need;  need += (size_t)GG * NN * 4;
    size_t off_bc = need;  need += (size_t)GG * NN * 4;
    if (ws_size < need) return;   // fail clean (absmax) instead of faulting the GPU

    char* ws = (char*)d_ws;
    float* f0 = (float*)(ws + off_f0);
    float* f1 = (float*)(ws + off_f1);
    float* Aa = (float*)(ws + off_A);
    float* Bv = (float*)(ws + off_B);
    unsigned int* adj = (unsigned int*)(ws + off_adj);
    int* nbr = (int*)(ws + off_nbr);
    int* valid = (int*)(ws + off_v);
    float* inv = (float*)(ws + off_inv);
    int* bcol = (int*)(ws + off_bc);

    k_input<<<(GG * NN * HH) / 256, 256, 0, stream>>>(x, dn, Win, bin, f0, valid);
    for (int L = 0; L < 2; ++L) {
        k_zero<<<(GG * NN * 32 + 255) / 256, 256, 0, stream>>>(adj, GG * NN * 32);
        k_knn<<<GG * NN / 8, 512, 0, stream>>>(f0, valid, nbr);
        k_mark<<<(GG * NN) / 256, 256, 0, stream>>>(nbr, valid, adj);
        k_ab<<<GG * NN, 128, 0, stream>>>(f0, W1[L], b1[L], Aa, Bv);
        k_edgeconv<<<GG * NN / 4, 256, 0, stream>>>(Aa, Bv, W2[L], b2[L], adj, valid, f1);
        k_deginv<<<(GG * NN) / 256, 256, 0, stream>>>(adj, valid, inv);
        k_graclus<<<GG * NN, 64, 0, stream>>>(f1, adj, inv, valid, bcol);
        k_pool<<<(GG * NN) / 4, 256, 0, stream>>>(f1, bcol, valid, f0);
    }
    k_head<<<GG, 256, 0, stream>>>(f0, valid, Wo1, bo1, Wo2, bo2, Wo3, bo3, out);
}